// Round 7
// baseline (388.448 us; speedup 1.0000x reference)
//
#include <hip/hip_runtime.h>
#include <stdint.h>

typedef __attribute__((ext_vector_type(4))) float f32x4;
typedef __attribute__((ext_vector_type(8))) __bf16 bf16x8;
typedef unsigned short u16;

#define AS1 __attribute__((address_space(1)))
#define AS3 __attribute__((address_space(3)))

__device__ __forceinline__ u16 f2bf(float f) {
  uint32_t u = __float_as_uint(f);
  u += 0x7fffu + ((u >> 16) & 1u);
  return (u16)(u >> 16);
}
__device__ __forceinline__ float bf2f(u16 s) {
  return __uint_as_float(((uint32_t)s) << 16);
}

__device__ __forceinline__ void gload_lds16(const void* g, void* l) {
  __builtin_amdgcn_global_load_lds((const AS1 void*)g, (AS3 void*)l, 16, 0, 0);
}

__device__ __forceinline__ bf16x8 ones_bf16x8() {
  uint32_t o4[4] = {0x3F803F80u, 0x3F803F80u, 0x3F803F80u, 0x3F803F80u};
  return *(bf16x8*)o4;
}

// ---------------------------------------------------------------------------
// [ROUND-7 NOTE: bit-identical resubmit of the round-6 source.  Round-6 bench
//  died with "container failed twice" (no diagnostics) -- third instance of
//  the signature that hit rounds 2 and 4, each of which passed on identical
//  resubmit (rounds 3, 5).  v5 sync-structure re-audit: RAW/WAR on the
//  parity-double-buffered A ledger verified; register WAR on bL covered by
//  in-order issue; all barriers block-uniform; bounds checked.]
// ---------------------------------------------------------------------------

// ---------------------------------------------------------------------------
// Kernel 0: f32 -> bf16 convert (x, w) + zero-init of ctxraw/colsum. [unchanged]
// ---------------------------------------------------------------------------
__global__ __launch_bounds__(256) void cvt_all(const float* __restrict__ X,
                                               const float* __restrict__ W,
                                               u16* __restrict__ x16,
                                               u16* __restrict__ w16,
                                               float* __restrict__ ctxbase) {
  const int gb = blockIdx.x;
  if (gb >= 9728) {
    const int idx = (gb - 9728) * 256 + threadIdx.x;
    for (int i = idx; i < 66560; i += 1024)
      ((f32x4*)ctxbase)[i] = (f32x4){0.f, 0.f, 0.f, 0.f};
    return;
  }
  const float* src;
  u16* dst;
  int i;
  if (gb < 8192) {
    src = X; dst = x16; i = gb * 256 + threadIdx.x;
  } else {
    src = W; dst = w16; i = (gb - 8192) * 256 + threadIdx.x;
  }
  const f32x4 a = ((const f32x4*)src)[2 * i];
  const f32x4 b = ((const f32x4*)src)[2 * i + 1];
  ushort4 lo, hi;
  lo.x = f2bf(a.x); lo.y = f2bf(a.y); lo.z = f2bf(a.z); lo.w = f2bf(a.w);
  hi.x = f2bf(b.x); hi.y = f2bf(b.y); hi.z = f2bf(b.z); hi.w = f2bf(b.w);
  ((ushort4*)dst)[2 * i] = lo;
  ((ushort4*)dst)[2 * i + 1] = hi;
}

// ---------------------------------------------------------------------------
// Kernel 1 v5: qkv = x @ w^T  (M=16384, K=1024, O=3072), bf16 in.
//  (a) B operand loaded global->REG (W panel is L2-resident; a B-frag is
//      16 cols x 64B contiguous per col = 4 dwordx4).  Deletes B staging,
//      the BL/BH LDS units, and 8 of 24 ds_read_b128 per tile.
//  (b) ONE barrier + ONE vmcnt(0) per K-TILE (was 4 barriers/tile).  A is
//      parity-double-buffered; all stages of tile t+1 target par^1, whose
//      last readers (tile t-1) finished before the previous boundary
//      barrier -> no intra-tile hazard.  vmcnt(0) at the boundary is free in
//      steady state (every load issued ~a full tile before its drain).
//      Waves free-run across the tile: ds_read || MFMA || stage overlap.
//  (c) LDS 128KB -> 64KB (2 parity x {AL,AH} x 16KB); Q-epilogue bounce
//      becomes 4 passes of 64 rows.
// Quadrant order Q00->Q01->Q10->Q11 so bL(t+1) issues right after Q10 (last
// bL(t) use) and arrives under Q11 + barrier.
// ---------------------------------------------------------------------------
__global__ __launch_bounds__(512, 2) void qkv_gemm(const u16* __restrict__ X,
                                                   const u16* __restrict__ W,
                                                   float* __restrict__ QOUT,
                                                   u16* __restrict__ KV) {
  __shared__ __attribute__((aligned(16))) u16 lds[4 * 128 * 64];  // 64 KiB

  const int t = threadIdx.x;
  const int D = blockIdx.x;
  const int xcd = D & 7;
  const int s = D >> 3;
  const int otile = s % 12;
  const int mtile = (s / 12) * 8 + xcd;
  const int oblk = otile << 8;
  const int mblk = mtile << 8;

  const int wv = t >> 6;
  const int l = t & 63;
  const int wm = wv >> 2;
  const int wnx = wv & 3;
  const int l15 = l & 15;
  const int lq = l >> 4;
  const int sp = t & 7;

  char* ldsc = (char*)lds;

  // --- A staging: unit = (par*2 + h), h 0=A-low(rows 0-63,128-191) 1=high --
  auto stageA = [&](int tau, int h, int par) {
#pragma unroll
    for (int j = 0; j < 2; j++) {
      const int ur = (j << 6) | (t >> 3);
      const int R = ((ur >> 6) << 7) | (h << 6) | (ur & 63);
      const u16* g = X + (size_t)(mblk + R) * 1024 + (tau << 6) +
                     ((sp ^ (ur & 7)) << 3);
      gload_lds16(g, ldsc + (((par << 1) | h) << 14) + (((j << 9) | t) << 4));
    }
  };

  // --- B direct global->reg: col = oblk + wnx*64 + nh*32 + fn*16 + l15,
  //     k = tau*64 + ks*32 + lk*8  (fragment-native, 16B/lane) --------------
  auto loadBg = [&](int tau, int nh, bf16x8(&bb)[2][2]) {
    const u16* base = W + (size_t)(oblk + (wnx << 6) + (nh << 5) + l15) * 1024 +
                      (tau << 6) + (lq << 3);
    bb[0][0] = *(const bf16x8*)(base);
    bb[0][1] = *(const bf16x8*)(base + 16 * 1024);
    bb[1][0] = *(const bf16x8*)(base + 32);
    bb[1][1] = *(const bf16x8*)(base + 16 * 1024 + 32);
  };

  const int co0 = (((l >> 4) ^ (l & 7)) << 4);
  const int co1 = ((((l >> 4) | 4) ^ (l & 7)) << 4);
  const int aOff = ((wm << 6) | l15) << 7;

  bf16x8 bA[2][4], bL[2][2], bH[2][2];
  auto loadA = [&](int h, int par) {
    const char* base = ldsc + (((par << 1) | h) << 14) + aOff;
#pragma unroll
    for (int fm = 0; fm < 4; fm++) {
      bA[0][fm] = *(const bf16x8*)(base + (fm << 11) + co0);
      bA[1][fm] = *(const bf16x8*)(base + (fm << 11) + co1);
    }
  };

  f32x4 acc[8][4];
#pragma unroll
  for (int i = 0; i < 8; i++)
#pragma unroll
    for (int j = 0; j < 4; j++) acc[i][j] = (f32x4){0.f, 0.f, 0.f, 0.f};

  auto mfma16 = [&](int ah, int nh, bf16x8(&bb)[2][2]) {
#pragma unroll
    for (int fm = 0; fm < 4; fm++)
#pragma unroll
      for (int fn = 0; fn < 2; fn++)
#pragma unroll
        for (int ks = 0; ks < 2; ks++)
          acc[(ah << 2) | fm][(nh << 1) | fn] =
              __builtin_amdgcn_mfma_f32_16x16x32_bf16(
                  bA[ks][fm], bb[ks][fn], acc[(ah << 2) | fm][(nh << 1) | fn],
                  0, 0, 0);
  };

  // --- prologue: stage A(0) into par0, bL(0) in flight ---------------------
  stageA(0, 0, 0);
  stageA(0, 1, 0);
  loadBg(0, 0, bL);
  asm volatile("s_waitcnt vmcnt(0)" ::: "memory");
  __builtin_amdgcn_s_barrier();

#pragma unroll 1
  for (int tau = 0; tau < 16; tau++) {
    const int par = tau & 1;
    if (tau < 15) {
      stageA(tau + 1, 0, par ^ 1);
      stageA(tau + 1, 1, par ^ 1);
    }
    loadBg(tau, 1, bH);  // bH(t): used by Q01/Q11 (compiler-counted wait)
    loadA(0, par);       // A-low frags (8 ds_read_b128)
    __builtin_amdgcn_s_setprio(1);
    mfma16(0, 0, bL);    // Q00
    mfma16(0, 1, bH);    // Q01
    __builtin_amdgcn_s_setprio(0);
    loadA(1, par);       // A-high frags
    __builtin_amdgcn_s_setprio(1);
    mfma16(1, 0, bL);    // Q10: last bL(t) use
    __builtin_amdgcn_s_setprio(0);
    if (tau < 15) loadBg(tau + 1, 0, bL);  // bL(t+1): arrives under Q11+barrier
    __builtin_amdgcn_s_setprio(1);
    mfma16(1, 1, bH);    // Q11
    __builtin_amdgcn_s_setprio(0);
    // boundary: all stages/loads of this tile are ~a full tile old -> drain
    // is empty in steady state; barrier publishes A(t+1) to all waves.
    asm volatile("s_waitcnt vmcnt(0)" ::: "memory");
    __builtin_amdgcn_s_barrier();
  }

  // --- epilogue ------------------------------------------------------------
  // C/D 16x16 layout: col=lane&15, row=(lane>>4)*4+reg  [m89-verified]
  const bool is_q = (oblk < 1024);
  if (is_q) {
    // bounce via LDS (64KB): 4 passes of 64 rows, then dwordx4 stores.
    float* LF = (float*)lds;
#pragma unroll 1
    for (int p = 0; p < 4; p++) {
      __syncthreads();
      if (wm == (p >> 1)) {
#pragma unroll
        for (int jf = 0; jf < 4; jf++) {
          const int j = ((p & 1) << 2) + jf;  // acc row-frag index 0..7
#pragma unroll
          for (int fn = 0; fn < 4; fn++) {
            const int colq = ((wnx << 2) | fn);  // col>>4
#pragma unroll
            for (int r = 0; r < 4; r++) {
              const int rl = (jf << 4) + (lq << 2) + r;  // row in pass 0..63
              const int g = colq ^ lq;  // (row>>2)&3 == lq
              LF[(rl << 8) + (g << 4) + l15] = acc[j][fn][r];
            }
          }
        }
      }
      __syncthreads();
      const int nbase = mblk + (wm == 0 ? 0 : 0) + (p << 6);
#pragma unroll
      for (int p8 = 0; p8 < 8; p8++) {
        const int u = (p8 << 9) + t;  // 0..4095 = 64 rows x 64 chunks
        const int row = u >> 6;
        const int c = u & 63;
        const int g = (c >> 2) ^ ((row >> 2) & 3);
        const f32x4 v4 = *(const f32x4*)&LF[(row << 8) + (g << 4) + ((c & 3) << 2)];
        const int rowg = nbase + row;
        const int bq = rowg >> 12, n = rowg & 4095;
        const int head = (oblk >> 6) + (c >> 4);
        *(f32x4*)&QOUT[((((size_t)((bq << 4) + head)) << 12) + n) * 64 +
                       ((c & 15) << 2)] = v4;
      }
    }
  } else {
    // fragment-native (tile-linear) KV [unchanged]
    u16* ks = KV + (((size_t)((mtile << 3) + (otile - 4))) << 16) + (wv << 13) +
              (l << 2);
#pragma unroll
    for (int fm = 0; fm < 8; fm++) {
#pragma unroll
      for (int fn = 0; fn < 4; fn++) {
        ushort4 sv;
        sv.x = f2bf(acc[fm][fn][0]);
        sv.y = f2bf(acc[fm][fn][1]);
        sv.z = f2bf(acc[fm][fn][2]);
        sv.w = f2bf(acc[fm][fn][3]);
        *(ushort4*)(ks + (((fm << 2) | fn) << 8)) = sv;
      }
    }
  }
}

// ---------------------------------------------------------------------------
// Kernel 2 v2 (MFMA): ctxraw[bh][d][e] += sum_n exp(k[n,d]) * v[n,e];
// colsum[bh][d] += sum_n exp(k[n,d]) via an extra B=ones MFMA. [unchanged]
// ---------------------------------------------------------------------------
__global__ __launch_bounds__(256) void ctx_colsum(const u16* __restrict__ KV,
                                                  float* __restrict__ ctxraw,
                                                  float* __restrict__ colsum) {
  __shared__ __attribute__((aligned(16))) u16 ekT[64 * 128];  // [d][n] swz
  __shared__ __attribute__((aligned(16))) u16 evT[64 * 128];  // [e][n] swz

  const int t = threadIdx.x;
  const int bh = blockIdx.y;
  const int b = bh >> 4, h = bh & 15;
  const int sgrp = blockIdx.x;  // 0..3 (n-split)
  const int w = t >> 6;
  const int l = t & 63;
  const int l15 = l & 15;
  const int lk = l >> 4;
  const int lq = (t >> 4) & 3;
  const int d_st = (w << 4) | l15;

  uint2 kr[8], vr[8];
  auto issue = [&](int it) {
    const int mt = (b << 4) + (sgrp << 2) + (it >> 1);
    const int wmb = it & 1;
    const size_t base = ((size_t)((mt << 3) + (h >> 2)) << 16) |
                        ((size_t)wmb << 15) | ((size_t)(h & 3) << 13) |
                        (size_t)(t << 2);
#pragma unroll
    for (int fm = 0; fm < 8; fm++) {
      kr[fm] = *(const uint2*)(KV + base + (fm << 10));
      vr[fm] = *(const uint2*)(KV + base + (fm << 10) + (4 << 16));
    }
  };
  auto stage = [&]() {
#pragma unroll
    for (int fm = 0; fm < 8; fm++) {
      const int c = (fm << 1) | (lq >> 1);
      const int off = (d_st << 8) + ((c ^ (d_st & 7)) << 4) + ((lq & 1) << 3);
      ushort4 es;
      es.x = f2bf(__expf(bf2f((u16)(kr[fm].x & 0xffff))));
      es.y = f2bf(__expf(bf2f((u16)(kr[fm].x >> 16))));
      es.z = f2bf(__expf(bf2f((u16)(kr[fm].y & 0xffff))));
      es.w = f2bf(__expf(bf2f((u16)(kr[fm].y >> 16))));
      *(ushort4*)((char*)ekT + off) = es;
      *(uint2*)((char*)evT + off) = vr[fm];
    }
  };

  f32x4 acc[4], acc1[4];
#pragma unroll
  for (int i = 0; i < 4; i++) {
    acc[i] = (f32x4){0.f, 0.f, 0.f, 0.f};
    acc1[i] = (f32x4){0.f, 0.f, 0.f, 0.f};
  }
  const bf16x8 ones = ones_bf16x8();
  const int eo = (w << 4) | l15;

  issue(0);
#pragma unroll 1
  for (int it = 0; it < 8; it++) {
    stage();
    if (it < 7) issue(it + 1);
    __syncthreads();
#pragma unroll
    for (int ksx = 0; ksx < 4; ksx++) {
      const bf16x8 bfrag = *(const bf16x8*)(
          (char*)evT + (eo << 8) + ((((ksx << 2) | lk) ^ (eo & 7)) << 4));
#pragma unroll
      for (int fmA = 0; fmA < 4; fmA++) {
        const int dA = (fmA << 4) | l15;
        const bf16x8 afrag = *(const bf16x8*)(
            (char*)ekT + (dA << 8) + ((((ksx << 2) | lk) ^ (dA & 7)) << 4));
        acc[fmA] = __builtin_amdgcn_mfma_f32_16x16x32_bf16(afrag, bfrag,
                                                           acc[fmA], 0, 0, 0);
        if (w == 0)
          acc1[fmA] = __builtin_amdgcn_mfma_f32_16x16x32_bf16(afrag, ones,
                                                              acc1[fmA], 0, 0, 0);
      }
    }
    __syncthreads();
  }

  float* dst = ctxraw + ((size_t)bh << 12);
#pragma unroll
  for (int fmA = 0; fmA < 4; fmA++)
#pragma unroll
    for (int r = 0; r < 4; r++) {
      const int d = (fmA << 4) + (lk << 2) + r;
      atomicAdd(&dst[(d << 6) + eo], acc[fmA][r]);
    }
  if (w == 0 && l15 == 0) {
#pragma unroll
    for (int fmA = 0; fmA < 4; fmA++)
#pragma unroll
      for (int r = 0; r < 4; r++) {
        const int d = (fmA << 4) + (lk << 2) + r;
        atomicAdd(&colsum[(bh << 6) + d], acc1[fmA][r]);
      }
  }
}

// ---------------------------------------------------------------------------
// Kernel 3 v2 (MFMA): out = (0.125/rowsum) * expq @ ctx'. [unchanged]
// ---------------------------------------------------------------------------
__global__ __launch_bounds__(256) void out_kernel(const float* __restrict__ ctxraw,
                                                  const float* __restrict__ colsum,
                                                  float* __restrict__ OUT) {
  __shared__ __attribute__((aligned(16))) u16 qe[256 * 64];   // [n][d] swz 32KB
  __shared__ __attribute__((aligned(16))) u16 ctxT[64 * 64];  // [e][d] swz 8KB

  const int t = threadIdx.x;
  const int bh = blockIdx.y;
  const int n0 = blockIdx.x << 8;
  const float* craw = ctxraw + ((size_t)bh << 12);
  float* qbase = OUT + ((size_t)bh * 4096 + n0) * 64;

#pragma unroll
  for (int p = 0; p < 4; p++) {
    const int vi = (p << 8) + t;
    const int d = vi >> 4;
    const int e4 = (vi & 15) << 2;
    const f32x4 cv = *(const f32x4*)(craw + (vi << 2));
    const float inv = 1.0f / colsum[(bh << 6) + d];
#pragma unroll
    for (int j = 0; j < 4; j++) {
      const int e = e4 + j;
      *(u16*)((char*)ctxT + (e << 7) + (((d >> 3) ^ (e & 7)) << 4) +
              ((d & 7) << 1)) = f2bf(cv[j] * inv);
    }
  }
#pragma unroll
  for (int p = 0; p < 16; p++) {
    const int idx = (p << 8) + t;
    const int row = idx >> 4;
    const int c4 = idx & 15;
    const f32x4 qv = *(const f32x4*)(qbase + (row << 6) + (c4 << 2));
    ushort4 ev;
    ev.x = f2bf(__expf(qv.x));
    ev.y = f2bf(__expf(qv.y));
    ev.z = f2bf(__expf(qv.z));
    ev.w = f2bf(__expf(qv.w));
    *(ushort4*)((char*)qe + (row << 7) + (((c4 >> 1) ^ (row & 7)) << 4) +
                ((c4 & 1) << 3)) = ev;
  }
  __syncthreads();

  const int w = t >> 6;
  const int l = t & 63;
  const int l15 = l & 15;
  const int lk = l >> 4;

  f32x4 acc[4][4], acc1[4];
#pragma unroll
  for (int i = 0; i < 4; i++) {
    acc1[i] = (f32x4){0.f, 0.f, 0.f, 0.f};
#pragma unroll
    for (int j = 0; j < 4; j++) acc[i][j] = (f32x4){0.f, 0.f, 0.f, 0.f};
  }
  const bf16x8 ones = ones_bf16x8();

#pragma unroll
  for (int ksx = 0; ksx < 2; ksx++) {
    bf16x8 bfr[4];
#pragma unroll
    for (int fn = 0; fn < 4; fn++) {
      const int e = (fn << 4) | l15;
      bfr[fn] = *(const bf16x8*)((char*)ctxT + (e << 7) +
                                 ((((ksx << 2) | lk) ^ (e & 7)) << 4));
    }
#pragma unroll
    for (int fm = 0; fm < 4; fm++) {
      const int row = (w << 6) | (fm << 4) | l15;
      const bf16x8 afr = *(const bf16x8*)(
          (char*)qe + (row << 7) + ((((ksx << 2) | lk) ^ (row & 7)) << 4));
      acc1[fm] = __builtin_amdgcn_mfma_f32_16x16x32_bf16(afr, ones, acc1[fm],
                                                         0, 0, 0);
#pragma unroll
      for (int fn = 0; fn < 4; fn++)
        acc[fm][fn] = __builtin_amdgcn_mfma_f32_16x16x32_bf16(afr, bfr[fn],
                                                              acc[fm][fn], 0, 0, 0);
    }
  }

#pragma unroll
  for (int fm = 0; fm < 4; fm++) {
#pragma unroll
    for (int r = 0; r < 4; r++) {
      const int row = (w << 6) + (fm << 4) + (lk << 2) + r;
      const float inv = 0.125f / acc1[fm][r];
#pragma unroll
      for (int fn = 0; fn < 4; fn++)
        qbase[(row << 6) + (fn << 4) + l15] = acc[fm][fn][r] * inv;
    }
  }
}

extern "C" void kernel_launch(void* const* d_in, const int* in_sizes, int n_in,
                              void* d_out, int out_size, void* d_ws, size_t ws_size,
                              hipStream_t stream) {
  const float* Xf = (const float*)d_in[0];
  const float* Wf = (const float*)d_in[1];

  u16* x16 = (u16*)d_ws;
  u16* w16 = x16 + (size_t)16384 * 1024;
  u16* KV = w16 + (size_t)3072 * 1024;
  float* ctxraw = (float*)(KV + (size_t)16384 * 2048);
  float* colsum = ctxraw + 64 * 64 * 64;
  float* QOUT = (float*)d_out;

  cvt_all<<<dim3(9732), 256, 0, stream>>>(Xf, Wf, x16, w16, ctxraw);
  qkv_gemm<<<dim3(768), 512, 0, stream>>>(x16, w16, QOUT, KV);
  ctx_colsum<<<dim3(4, 64), 256, 0, stream>>>(KV, ctxraw, colsum);
  out_kernel<<<dim3(16, 64), 256, 0, stream>>>(ctxraw, colsum, QOUT);
}

// Round 8
// 258.586 us; speedup vs baseline: 1.5022x; 1.5022x over previous
//
#include <hip/hip_runtime.h>
#include <stdint.h>

typedef __attribute__((ext_vector_type(4))) float f32x4;
typedef __attribute__((ext_vector_type(8))) __bf16 bf16x8;
typedef unsigned short u16;

#define AS1 __attribute__((address_space(1)))
#define AS3 __attribute__((address_space(3)))

__device__ __forceinline__ u16 f2bf(float f) {
  uint32_t u = __float_as_uint(f);
  u += 0x7fffu + ((u >> 16) & 1u);
  return (u16)(u >> 16);
}
__device__ __forceinline__ float bf2f(u16 s) {
  return __uint_as_float(((uint32_t)s) << 16);
}

__device__ __forceinline__ void gload_lds16(const void* g, void* l) {
  __builtin_amdgcn_global_load_lds((const AS1 void*)g, (AS3 void*)l, 16, 0, 0);
}

__device__ __forceinline__ bf16x8 ones_bf16x8() {
  uint32_t o4[4] = {0x3F803F80u, 0x3F803F80u, 0x3F803F80u, 0x3F803F80u};
  return *(bf16x8*)o4;
}

// ---------------------------------------------------------------------------
// Kernel 0: f32 -> bf16 convert (x, w) + zero-init of ctxraw/colsum. [unchanged]
// ---------------------------------------------------------------------------
__global__ __launch_bounds__(256) void cvt_all(const float* __restrict__ X,
                                               const float* __restrict__ W,
                                               u16* __restrict__ x16,
                                               u16* __restrict__ w16,
                                               float* __restrict__ ctxbase) {
  const int gb = blockIdx.x;
  if (gb >= 9728) {
    const int idx = (gb - 9728) * 256 + threadIdx.x;
    for (int i = idx; i < 66560; i += 1024)
      ((f32x4*)ctxbase)[i] = (f32x4){0.f, 0.f, 0.f, 0.f};
    return;
  }
  const float* src;
  u16* dst;
  int i;
  if (gb < 8192) {
    src = X; dst = x16; i = gb * 256 + threadIdx.x;
  } else {
    src = W; dst = w16; i = (gb - 8192) * 256 + threadIdx.x;
  }
  const f32x4 a = ((const f32x4*)src)[2 * i];
  const f32x4 b = ((const f32x4*)src)[2 * i + 1];
  ushort4 lo, hi;
  lo.x = f2bf(a.x); lo.y = f2bf(a.y); lo.z = f2bf(a.z); lo.w = f2bf(a.w);
  hi.x = f2bf(b.x); hi.y = f2bf(b.y); hi.z = f2bf(b.z); hi.w = f2bf(b.w);
  ((ushort4*)dst)[2 * i] = lo;
  ((ushort4*)dst)[2 * i + 1] = hi;
}

// ---------------------------------------------------------------------------
// Kernel 1 v6: qkv = x @ w^T  (M=16384, K=1024, O=3072), bf16 in.
// POST-MORTEM v5: B global->reg caused register spills (WRITE_SIZE 131->524MB
// = scratch traffic; VGPR_Count 124->112 = allocator spilling; dur = 713MB /
// 3.16TB/s).  acc=128 AGPR leaves no headroom for register-resident B.
// v6 = v4's PROVEN B-in-LDS staging (124 VGPR, no spill, 128 KiB LDS)
//    + v5's ONE barrier + ONE vmcnt(0) per K-TILE (v4 had 4 barriers + 4
//      lgkm drains per tile, which serialized LDS-read bursts against MFMA
//      bursts -> 4843 cyc/tile vs ~3000 overlapped floor).
// Hazard ledger: stages at iter t write only par^1; par^1's last readers
// (iter t-1) completed before the end-of-(t-1) barrier (lgkmcnt orders
// read->MFMA->barrier per wave).  RAW on staged data: boundary vmcnt(0) +
// barrier.  Intra-tile ds_read RAW: compiler lgkmcnt.  bL/bH live only
// within one tile -> no cross-tile register state -> no spill.
// ---------------------------------------------------------------------------
__global__ __launch_bounds__(512, 2) void qkv_gemm(const u16* __restrict__ X,
                                                   const u16* __restrict__ W,
                                                   float* __restrict__ QOUT,
                                                   u16* __restrict__ KV) {
  __shared__ __attribute__((aligned(16))) u16 lds[8 * 128 * 64];  // 128 KiB

  const int t = threadIdx.x;
  const int D = blockIdx.x;
  const int xcd = D & 7;
  const int s = D >> 3;
  const int otile = s % 12;
  const int mtile = (s / 12) * 8 + xcd;
  const int oblk = otile << 8;
  const int mblk = mtile << 8;

  const int wv = t >> 6;
  const int l = t & 63;
  const int wm = wv >> 2;
  const int wnx = wv & 3;
  const int l15 = l & 15;
  const int lq = l >> 4;
  const int sp = t & 7;

  char* ldsc = (char*)lds;

  // --- staging: unit u = (par*4 + type), type 0=AL 1=AH 2=BL 3=BH ----------
  auto stageA = [&](int tau, int h, int par) {
#pragma unroll
    for (int j = 0; j < 2; j++) {
      const int ur = (j << 6) | (t >> 3);
      const int R = ((ur >> 6) << 7) | (h << 6) | (ur & 63);
      const u16* g = X + (size_t)(mblk + R) * 1024 + (tau << 6) +
                     ((sp ^ (ur & 7)) << 3);
      gload_lds16(g, ldsc + (((par << 2) | h) << 14) + (((j << 9) | t) << 4));
    }
  };
  auto stageB = [&](int tau, int h, int par) {
#pragma unroll
    for (int j = 0; j < 2; j++) {
      const int ur = (j << 6) | (t >> 3);
      const int R = ((ur >> 5) << 6) | (h << 5) | (ur & 31);
      const u16* g = W + (size_t)(oblk + R) * 1024 + (tau << 6) +
                     ((sp ^ (ur & 7)) << 3);
      gload_lds16(g,
                  ldsc + (((par << 2) | 2 | h) << 14) + (((j << 9) | t) << 4));
    }
  };

  const int co0 = (((l >> 4) ^ (l & 7)) << 4);
  const int co1 = ((((l >> 4) | 4) ^ (l & 7)) << 4);
  const int aOff = ((wm << 6) | l15) << 7;
  const int bOff = ((wnx << 5) | l15) << 7;

  bf16x8 bA[2][4], bL[2][2], bH[2][2];
  auto loadA = [&](int h, int par) {
    const char* base = ldsc + (((par << 2) | h) << 14) + aOff;
#pragma unroll
    for (int fm = 0; fm < 4; fm++) {
      bA[0][fm] = *(const bf16x8*)(base + (fm << 11) + co0);
      bA[1][fm] = *(const bf16x8*)(base + (fm << 11) + co1);
    }
  };
  auto loadB2 = [&](int nh, int par, bf16x8(&bb)[2][2]) {
    const char* base = ldsc + (((par << 2) | 2 | nh) << 14) + bOff;
#pragma unroll
    for (int fn = 0; fn < 2; fn++) {
      bb[0][fn] = *(const bf16x8*)(base + (fn << 11) + co0);
      bb[1][fn] = *(const bf16x8*)(base + (fn << 11) + co1);
    }
  };

  f32x4 acc[8][4];
#pragma unroll
  for (int i = 0; i < 8; i++)
#pragma unroll
    for (int j = 0; j < 4; j++) acc[i][j] = (f32x4){0.f, 0.f, 0.f, 0.f};

  auto mfma16 = [&](int ah, int nh, bf16x8(&bb)[2][2]) {
#pragma unroll
    for (int fm = 0; fm < 4; fm++)
#pragma unroll
      for (int fn = 0; fn < 2; fn++)
#pragma unroll
        for (int ks = 0; ks < 2; ks++)
          acc[(ah << 2) | fm][(nh << 1) | fn] =
              __builtin_amdgcn_mfma_f32_16x16x32_bf16(
                  bA[ks][fm], bb[ks][fn], acc[(ah << 2) | fm][(nh << 1) | fn],
                  0, 0, 0);
  };

  // --- prologue: stage all 4 units of tile 0 into par 0 --------------------
  stageA(0, 0, 0);
  stageA(0, 1, 0);
  stageB(0, 0, 0);
  stageB(0, 1, 0);
  asm volatile("s_waitcnt vmcnt(0)" ::: "memory");
  __builtin_amdgcn_s_barrier();

#pragma unroll 1
  for (int tau = 0; tau < 16; tau++) {
    const int par = tau & 1;
    if (tau < 15) {
      stageA(tau + 1, 0, par ^ 1);
      stageA(tau + 1, 1, par ^ 1);
      stageB(tau + 1, 0, par ^ 1);
      stageB(tau + 1, 1, par ^ 1);
    }
    loadA(0, par);
    loadB2(0, par, bL);
    loadB2(1, par, bH);
    __builtin_amdgcn_s_setprio(1);
    mfma16(0, 0, bL);  // Q00
    mfma16(0, 1, bH);  // Q01
    __builtin_amdgcn_s_setprio(0);
    loadA(1, par);
    __builtin_amdgcn_s_setprio(1);
    mfma16(1, 1, bH);  // Q11
    mfma16(1, 0, bL);  // Q10
    __builtin_amdgcn_s_setprio(0);
    // single boundary: drain this tile's 8 staging loads (issued ~a full
    // tile ago -> near-empty) and publish par^1 to all waves.
    asm volatile("s_waitcnt vmcnt(0)" ::: "memory");
    __builtin_amdgcn_s_barrier();
  }

  // --- epilogue ------------------------------------------------------------
  // C/D 16x16 layout: col=lane&15, row=(lane>>4)*4+reg  [m89-verified]
  const bool is_q = (oblk < 1024);
  if (is_q) {
    // bounce through LDS (dead after main loop), 2 passes of 128 rows.
    float* LF = (float*)lds;
#pragma unroll 1
    for (int hh = 0; hh < 2; hh++) {
      __syncthreads();
      if (wm == hh) {
#pragma unroll
        for (int fm = 0; fm < 8; fm++) {
#pragma unroll
          for (int fn = 0; fn < 4; fn++) {
            const int colq = ((wnx << 2) | fn);  // col>>4
#pragma unroll
            for (int r = 0; r < 4; r++) {
              const int row = (fm << 4) + (lq << 2) + r;  // local 0..127
              const int g = colq ^ lq;                    // (row>>2)&3 == lq
              LF[(row << 8) + (g << 4) + l15] = acc[fm][fn][r];
            }
          }
        }
      }
      __syncthreads();
      const int nbase = mblk + (hh << 7);
#pragma unroll
      for (int p = 0; p < 16; p++) {
        const int u = (p << 9) + t;  // 0..8191 = 128 rows x 64 chunks
        const int row = u >> 6;
        const int c = u & 63;
        const int g = (c >> 2) ^ ((row >> 2) & 3);
        const f32x4 v4 = *(const f32x4*)&LF[(row << 8) + (g << 4) + ((c & 3) << 2)];
        const int rowg = nbase + row;
        const int bq = rowg >> 12, n = rowg & 4095;
        const int head = (oblk >> 6) + (c >> 4);
        *(f32x4*)&QOUT[((((size_t)((bq << 4) + head)) << 12) + n) * 64 +
                       ((c & 15) << 2)] = v4;
      }
    }
  } else {
    // fragment-native (tile-linear) KV [unchanged]
    u16* ks = KV + (((size_t)((mtile << 3) + (otile - 4))) << 16) + (wv << 13) +
              (l << 2);
#pragma unroll
    for (int fm = 0; fm < 8; fm++) {
#pragma unroll
      for (int fn = 0; fn < 4; fn++) {
        ushort4 sv;
        sv.x = f2bf(acc[fm][fn][0]);
        sv.y = f2bf(acc[fm][fn][1]);
        sv.z = f2bf(acc[fm][fn][2]);
        sv.w = f2bf(acc[fm][fn][3]);
        *(ushort4*)(ks + (((fm << 2) | fn) << 8)) = sv;
      }
    }
  }
}

// ---------------------------------------------------------------------------
// Kernel 2 v2 (MFMA): ctxraw[bh][d][e] += sum_n exp(k[n,d]) * v[n,e];
// colsum[bh][d] += sum_n exp(k[n,d]) via an extra B=ones MFMA. [unchanged]
// ---------------------------------------------------------------------------
__global__ __launch_bounds__(256) void ctx_colsum(const u16* __restrict__ KV,
                                                  float* __restrict__ ctxraw,
                                                  float* __restrict__ colsum) {
  __shared__ __attribute__((aligned(16))) u16 ekT[64 * 128];  // [d][n] swz
  __shared__ __attribute__((aligned(16))) u16 evT[64 * 128];  // [e][n] swz

  const int t = threadIdx.x;
  const int bh = blockIdx.y;
  const int b = bh >> 4, h = bh & 15;
  const int sgrp = blockIdx.x;  // 0..3 (n-split)
  const int w = t >> 6;
  const int l = t & 63;
  const int l15 = l & 15;
  const int lk = l >> 4;
  const int lq = (t >> 4) & 3;
  const int d_st = (w << 4) | l15;

  uint2 kr[8], vr[8];
  auto issue = [&](int it) {
    const int mt = (b << 4) + (sgrp << 2) + (it >> 1);
    const int wmb = it & 1;
    const size_t base = ((size_t)((mt << 3) + (h >> 2)) << 16) |
                        ((size_t)wmb << 15) | ((size_t)(h & 3) << 13) |
                        (size_t)(t << 2);
#pragma unroll
    for (int fm = 0; fm < 8; fm++) {
      kr[fm] = *(const uint2*)(KV + base + (fm << 10));
      vr[fm] = *(const uint2*)(KV + base + (fm << 10) + (4 << 16));
    }
  };
  auto stage = [&]() {
#pragma unroll
    for (int fm = 0; fm < 8; fm++) {
      const int c = (fm << 1) | (lq >> 1);
      const int off = (d_st << 8) + ((c ^ (d_st & 7)) << 4) + ((lq & 1) << 3);
      ushort4 es;
      es.x = f2bf(__expf(bf2f((u16)(kr[fm].x & 0xffff))));
      es.y = f2bf(__expf(bf2f((u16)(kr[fm].x >> 16))));
      es.z = f2bf(__expf(bf2f((u16)(kr[fm].y & 0xffff))));
      es.w = f2bf(__expf(bf2f((u16)(kr[fm].y >> 16))));
      *(ushort4*)((char*)ekT + off) = es;
      *(uint2*)((char*)evT + off) = vr[fm];
    }
  };

  f32x4 acc[4], acc1[4];
#pragma unroll
  for (int i = 0; i < 4; i++) {
    acc[i] = (f32x4){0.f, 0.f, 0.f, 0.f};
    acc1[i] = (f32x4){0.f, 0.f, 0.f, 0.f};
  }
  const bf16x8 ones = ones_bf16x8();
  const int eo = (w << 4) | l15;

  issue(0);
#pragma unroll 1
  for (int it = 0; it < 8; it++) {
    stage();
    if (it < 7) issue(it + 1);
    __syncthreads();
#pragma unroll
    for (int ksx = 0; ksx < 4; ksx++) {
      const bf16x8 bfrag = *(const bf16x8*)(
          (char*)evT + (eo << 8) + ((((ksx << 2) | lk) ^ (eo & 7)) << 4));
#pragma unroll
      for (int fmA = 0; fmA < 4; fmA++) {
        const int dA = (fmA << 4) | l15;
        const bf16x8 afrag = *(const bf16x8*)(
            (char*)ekT + (dA << 8) + ((((ksx << 2) | lk) ^ (dA & 7)) << 4));
        acc[fmA] = __builtin_amdgcn_mfma_f32_16x16x32_bf16(afrag, bfrag,
                                                           acc[fmA], 0, 0, 0);
        if (w == 0)
          acc1[fmA] = __builtin_amdgcn_mfma_f32_16x16x32_bf16(afrag, ones,
                                                              acc1[fmA], 0, 0, 0);
      }
    }
    __syncthreads();
  }

  float* dst = ctxraw + ((size_t)bh << 12);
#pragma unroll
  for (int fmA = 0; fmA < 4; fmA++)
#pragma unroll
    for (int r = 0; r < 4; r++) {
      const int d = (fmA << 4) + (lk << 2) + r;
      atomicAdd(&dst[(d << 6) + eo], acc[fmA][r]);
    }
  if (w == 0 && l15 == 0) {
#pragma unroll
    for (int fmA = 0; fmA < 4; fmA++)
#pragma unroll
      for (int r = 0; r < 4; r++) {
        const int d = (fmA << 4) + (lk << 2) + r;
        atomicAdd(&colsum[(bh << 6) + d], acc1[fmA][r]);
      }
  }
}

// ---------------------------------------------------------------------------
// Kernel 3 v2 (MFMA): out = (0.125/rowsum) * expq @ ctx'. [unchanged]
// ---------------------------------------------------------------------------
__global__ __launch_bounds__(256) void out_kernel(const float* __restrict__ ctxraw,
                                                  const float* __restrict__ colsum,
                                                  float* __restrict__ OUT) {
  __shared__ __attribute__((aligned(16))) u16 qe[256 * 64];   // [n][d] swz 32KB
  __shared__ __attribute__((aligned(16))) u16 ctxT[64 * 64];  // [e][d] swz 8KB

  const int t = threadIdx.x;
  const int bh = blockIdx.y;
  const int n0 = blockIdx.x << 8;
  const float* craw = ctxraw + ((size_t)bh << 12);
  float* qbase = OUT + ((size_t)bh * 4096 + n0) * 64;

#pragma unroll
  for (int p = 0; p < 4; p++) {
    const int vi = (p << 8) + t;
    const int d = vi >> 4;
    const int e4 = (vi & 15) << 2;
    const f32x4 cv = *(const f32x4*)(craw + (vi << 2));
    const float inv = 1.0f / colsum[(bh << 6) + d];
#pragma unroll
    for (int j = 0; j < 4; j++) {
      const int e = e4 + j;
      *(u16*)((char*)ctxT + (e << 7) + (((d >> 3) ^ (e & 7)) << 4) +
              ((d & 7) << 1)) = f2bf(cv[j] * inv);
    }
  }
#pragma unroll
  for (int p = 0; p < 16; p++) {
    const int idx = (p << 8) + t;
    const int row = idx >> 4;
    const int c4 = idx & 15;
    const f32x4 qv = *(const f32x4*)(qbase + (row << 6) + (c4 << 2));
    ushort4 ev;
    ev.x = f2bf(__expf(qv.x));
    ev.y = f2bf(__expf(qv.y));
    ev.z = f2bf(__expf(qv.z));
    ev.w = f2bf(__expf(qv.w));
    *(ushort4*)((char*)qe + (row << 7) + (((c4 >> 1) ^ (row & 7)) << 4) +
                ((c4 & 1) << 3)) = ev;
  }
  __syncthreads();

  const int w = t >> 6;
  const int l = t & 63;
  const int l15 = l & 15;
  const int lk = l >> 4;

  f32x4 acc[4][4], acc1[4];
#pragma unroll
  for (int i = 0; i < 4; i++) {
    acc1[i] = (f32x4){0.f, 0.f, 0.f, 0.f};
#pragma unroll
    for (int j = 0; j < 4; j++) acc[i][j] = (f32x4){0.f, 0.f, 0.f, 0.f};
  }
  const bf16x8 ones = ones_bf16x8();

#pragma unroll
  for (int ksx = 0; ksx < 2; ksx++) {
    bf16x8 bfr[4];
#pragma unroll
    for (int fn = 0; fn < 4; fn++) {
      const int e = (fn << 4) | l15;
      bfr[fn] = *(const bf16x8*)((char*)ctxT + (e << 7) +
                                 ((((ksx << 2) | lk) ^ (e & 7)) << 4));
    }
#pragma unroll
    for (int fm = 0; fm < 4; fm++) {
      const int row = (w << 6) | (fm << 4) | l15;
      const bf16x8 afr = *(const bf16x8*)(
          (char*)qe + (row << 7) + ((((ksx << 2) | lk) ^ (row & 7)) << 4));
      acc1[fm] = __builtin_amdgcn_mfma_f32_16x16x32_bf16(afr, ones, acc1[fm],
                                                         0, 0, 0);
#pragma unroll
      for (int fn = 0; fn < 4; fn++)
        acc[fm][fn] = __builtin_amdgcn_mfma_f32_16x16x32_bf16(afr, bfr[fn],
                                                              acc[fm][fn], 0, 0, 0);
    }
  }

#pragma unroll
  for (int fm = 0; fm < 4; fm++) {
#pragma unroll
    for (int r = 0; r < 4; r++) {
      const int row = (w << 6) + (fm << 4) + (lk << 2) + r;
      const float inv = 0.125f / acc1[fm][r];
#pragma unroll
      for (int fn = 0; fn < 4; fn++)
        qbase[(row << 6) + (fn << 4) + l15] = acc[fm][fn][r] * inv;
    }
  }
}

extern "C" void kernel_launch(void* const* d_in, const int* in_sizes, int n_in,
                              void* d_out, int out_size, void* d_ws, size_t ws_size,
                              hipStream_t stream) {
  const float* Xf = (const float*)d_in[0];
  const float* Wf = (const float*)d_in[1];

  u16* x16 = (u16*)d_ws;
  u16* w16 = x16 + (size_t)16384 * 1024;
  u16* KV = w16 + (size_t)3072 * 1024;
  float* ctxraw = (float*)(KV + (size_t)16384 * 2048);
  float* colsum = ctxraw + 64 * 64 * 64;
  float* QOUT = (float*)d_out;

  cvt_all<<<dim3(9732), 256, 0, stream>>>(Xf, Wf, x16, w16, ctxraw);
  qkv_gemm<<<dim3(768), 512, 0, stream>>>(x16, w16, QOUT, KV);
  ctx_colsum<<<dim3(4, 64), 256, 0, stream>>>(KV, ctxraw, colsum);
  out_kernel<<<dim3(16, 64), 256, 0, stream>>>(ctxraw, colsum, QOUT);
}